// Round 4
// baseline (415.776 us; speedup 1.0000x reference)
//
#include <hip/hip_runtime.h>

// B=32, C=512, c2=256, M=1024. All GEMMs bf16 MFMA (fp32 accum), m97-style:
// 128x128 (or fused) tiles, BK=64, global_load_lds(16B) staging, XOR-swizzled
// chunks.
//
// P0 : x[b][c][sp] fp32 -> xT[b*1024+sp][c] bf16
// W0 : weight casts (Wkv = [Wk;Wv] 512x512, Wo 512x256)
// K1 : [32768x512]x[512x512]: k-half -> kT[m][c] + row-sum partials,
//      v-half -> vT[b][c][n] (reshape-permuted)
// K1b: combine 4 row-sum partials -> s_buf
// K2 : FUSED flash-style attention per (64-row m-stripe, batch), software-
//      pipelined: 8 uniform 16KB stages per 128-n chunk (4 S-GEMM K-steps,
//      4 PV steps), ONE barrier per stage, depth-1 prefetch into ping-pong
//      staging so the vmcnt(0)-at-barrier drain is hidden by a stage of
//      compute. A(kT stripe) resident in LDS; P kept in LDS (A-operand
//      layout); epilogue: rowsum reduce + normalize + OB write.
// K3 : out = Wo @ O2 + bo + x (fp32), B = OB (k-major)

typedef short bf8 __attribute__((ext_vector_type(8)));
typedef float f32x4 __attribute__((ext_vector_type(4)));

#define MFMA16(a, b, c) __builtin_amdgcn_mfma_f32_16x16x32_bf16((a), (b), (c), 0, 0, 0)

__device__ __forceinline__ short f2bf(float x) {
  unsigned u = __float_as_uint(x);
  u += 0x7fffu + ((u >> 16) & 1u);   // RNE, finite inputs
  return (short)(u >> 16);
}

__device__ __forceinline__ void gll16(const short* g, void* l) {
  __builtin_amdgcn_global_load_lds(
      (const __attribute__((address_space(1))) unsigned int*)g,
      (__attribute__((address_space(3))) unsigned int*)l, 16, 0, 0);
}

// ---- shared GEMM core: C[128][128] tile, A/B k-major bf16, K = ksteps*64 ----
__device__ __forceinline__ void gemm_core(const short* __restrict__ A,
                                          const short* __restrict__ B,
                                          int ldA, int ldB, int ksteps,
                                          char* smem, f32x4 acc[4][4]) {
  const int tid = threadIdx.x;
  const int w = tid >> 6, l = tid & 63;
  const int q = l >> 4, i = l & 15;
  const int wm = w & 1, wn = w >> 1;
  const int srow = l >> 3;
  const int gcol = ((l & 7) ^ srow) * 8;        // swizzled 16B chunk (shorts)
  f32x4 zz = {0.f, 0.f, 0.f, 0.f};
  #pragma unroll
  for (int mt = 0; mt < 4; ++mt)
    #pragma unroll
    for (int nt = 0; nt < 4; ++nt) acc[mt][nt] = zz;

  for (int ks = 0; ks < ksteps; ++ks) {
    __syncthreads();                            // LDS free (prev reads done)
    const short* Ak = A + ks * 64 + gcol;
    const short* Bk = B + ks * 64 + gcol;
    #pragma unroll
    for (int j = 0; j < 4; ++j) {
      int s = w * 4 + j;
      size_t row = (size_t)(s * 8 + srow);
      gll16(Ak + row * ldA, smem + s * 1024);
      gll16(Bk + row * ldB, smem + 16384 + s * 1024);
    }
    __syncthreads();                            // staged data visible
    #pragma unroll
    for (int kq = 0; kq < 2; ++kq) {
      int sw = ((kq * 4 + q) ^ (i & 7)) * 16;   // swizzled read offset (bytes)
      bf8 af[4], bq[4];
      #pragma unroll
      for (int mt = 0; mt < 4; ++mt)
        af[mt] = *(const bf8*)(smem + (wm * 64 + mt * 16 + i) * 128 + sw);
      #pragma unroll
      for (int nt = 0; nt < 4; ++nt)
        bq[nt] = *(const bf8*)(smem + 16384 + (wn * 64 + nt * 16 + i) * 128 + sw);
      #pragma unroll
      for (int mt = 0; mt < 4; ++mt)
        #pragma unroll
        for (int nt = 0; nt < 4; ++nt)
          acc[mt][nt] = MFMA16(af[mt], bq[nt], acc[mt][nt]);
    }
  }
}

// ---------------- P0: transpose + convert x ----------------
__global__ __launch_bounds__(256) void p0_xpose(const float* __restrict__ x,
                                                short* __restrict__ xT) {
  __shared__ float lds[64][65];
  int cb = blockIdx.x, sb = blockIdx.y, b = blockIdx.z;
  int t = threadIdx.x;
  int c0 = cb * 64, sp0 = sb * 64;
  const float4* x4 = reinterpret_cast<const float4*>(x);
  #pragma unroll
  for (int j = 0; j < 4; ++j) {
    int lin = t + 256 * j;
    int cl = lin >> 4, s4 = lin & 15;
    float4 v = x4[(((size_t)b * 512 + c0 + cl) * 1024 + sp0 + s4 * 4) >> 2];
    lds[cl][s4 * 4 + 0] = v.x; lds[cl][s4 * 4 + 1] = v.y;
    lds[cl][s4 * 4 + 2] = v.z; lds[cl][s4 * 4 + 3] = v.w;
  }
  __syncthreads();
  int spl = t >> 2, cs = (t & 3) * 16;
  bf8 o0, o1;
  #pragma unroll
  for (int j = 0; j < 8; ++j) o0[j] = f2bf(lds[cs + j][spl]);
  #pragma unroll
  for (int j = 0; j < 8; ++j) o1[j] = f2bf(lds[cs + 8 + j][spl]);
  size_t base = ((size_t)b * 1024 + sp0 + spl) * 512 + c0 + cs;
  *reinterpret_cast<bf8*>(xT + base) = o0;
  *reinterpret_cast<bf8*>(xT + base + 8) = o1;
}

// ---------------- W0: weight casts ----------------
__global__ __launch_bounds__(256) void w0_weights(const float* __restrict__ Wk,
                                                  const float* __restrict__ Wv,
                                                  const float* __restrict__ Wo,
                                                  short* __restrict__ Wkv_bf,
                                                  short* __restrict__ Wo_bf) {
  int g = blockIdx.x * 256 + threadIdx.x;
  if (g < 262144) {
    int o = g >> 9, c = g & 511;
    float v = (o < 256) ? Wk[o * 512 + c] : Wv[(o - 256) * 512 + c];
    Wkv_bf[g] = f2bf(v);
  } else {
    int i2 = g - 262144;
    Wo_bf[i2] = f2bf(Wo[i2]);
  }
}

// ---------------- K1: fused k/v projection GEMM ----------------
__global__ __launch_bounds__(256, 2) void k1_kv(const short* __restrict__ xT,
                                                const short* __restrict__ Wkv,
                                                const float* __restrict__ bk,
                                                const float* __restrict__ bv,
                                                short* __restrict__ kT,
                                                short* __restrict__ vT,
                                                float* __restrict__ s_part) {
  __shared__ __attribute__((aligned(16))) char smem[32768];
  f32x4 acc[4][4];
  int bm = blockIdx.x, bn = blockIdx.y;
  gemm_core(xT + (size_t)bm * 128 * 512, Wkv + (size_t)bn * 128 * 512,
            512, 512, 8, smem, acc);
  int tid = threadIdx.x;
  int w = tid >> 6, l = tid & 63, q = l >> 4, i = l & 15;
  int wm = w & 1, wn = w >> 1;
  int mbase = bm * 128 + wm * 64;
  int nbase = bn * 128 + wn * 64;
  if (bn < 2) {                                  // k half
    float rp[4][4];
    #pragma unroll
    for (int mt = 0; mt < 4; ++mt)
      #pragma unroll
      for (int r = 0; r < 4; ++r) rp[mt][r] = 0.f;
    #pragma unroll
    for (int mt = 0; mt < 4; ++mt)
      #pragma unroll
      for (int nt = 0; nt < 4; ++nt) {
        float bias = bk[nbase + nt * 16 + i];
        #pragma unroll
        for (int r = 0; r < 4; ++r) {
          float val = acc[mt][nt][r] + bias;
          int mg = mbase + mt * 16 + q * 4 + r;
          kT[(size_t)mg * 256 + nbase + nt * 16 + i] = f2bf(val);
          rp[mt][r] += val;
        }
      }
    #pragma unroll
    for (int mask = 1; mask <= 8; mask <<= 1)
      #pragma unroll
      for (int mt = 0; mt < 4; ++mt)
        #pragma unroll
        for (int r = 0; r < 4; ++r) rp[mt][r] += __shfl_xor(rp[mt][r], mask, 64);
    if (i == 0) {
      int pg = bn * 2 + wn;
      #pragma unroll
      for (int mt = 0; mt < 4; ++mt)
        #pragma unroll
        for (int r = 0; r < 4; ++r)
          s_part[pg * 32768 + mbase + mt * 16 + q * 4 + r] = rp[mt][r];
    }
  } else {                                       // v half -> vT permuted
    #pragma unroll
    for (int mt = 0; mt < 4; ++mt)
      #pragma unroll
      for (int nt = 0; nt < 4; ++nt) {
        int o2 = nbase + nt * 16 + i - 256;
        float bias = bv[o2];
        #pragma unroll
        for (int r = 0; r < 4; ++r) {
          float val = acc[mt][nt][r] + bias;
          int mg = mbase + mt * 16 + q * 4 + r;
          int b = mg >> 10, sp = mg & 1023;
          vT[((size_t)b * 256 + (sp & 255)) * 1024 + 4 * o2 + (sp >> 8)] = f2bf(val);
        }
      }
  }
}

__global__ __launch_bounds__(256) void k1b_sum(const float* __restrict__ s_part,
                                               float* __restrict__ s_buf) {
  int t = blockIdx.x * 256 + threadIdx.x;
  s_buf[t] = s_part[t] + s_part[32768 + t] + s_part[65536 + t] + s_part[98304 + t];
}

// ---------------- K2: pipelined fused gram -> softmax -> PV -> OB ----------
// Block = (64-row m-stripe bm, batch b). 8 uniform stages per 128-n chunk:
//   gs 0..3 : S-GEMM K-step ks=gs (B = kT rows [n0,n0+128) staged 16KB)
//   gs 4..7 : PV step (kh=(gs-4)>>1 selects n-half, ch=(gs-4)&1 c-half;
//             B = vT rows [ch*128,+128) x n-cols [n0+kh*64,+64) staged 16KB)
// One __syncthreads per stage; prefetch of stage g+1 issued right after the
// sync so its latency is hidden behind stage g's compute.
// LDS: Apan 32K (resident kT stripe) | Ppan 16K (P, A-layout) | 2x16K pingpong.
__global__ __launch_bounds__(256, 2) void k2_fused(const short* __restrict__ kT,
                                                   const short* __restrict__ vT,
                                                   const float* __restrict__ s_buf,
                                                   short* __restrict__ OB) {
  __shared__ __attribute__((aligned(16))) char smem[81920];
  char* Apan = smem;            // 4 panels x (64 rows x 128 B)
  char* Ppan = smem + 32768;    // 2 panels x (64 rows x 128 B)
  char* Bst  = smem + 49152;    // 2 x 16KB ping-pong staging

  const int bm = blockIdx.x, b = blockIdx.y;
  const int tid = threadIdx.x;
  const int w = tid >> 6, l = tid & 63;
  const int q = l >> 4, i = l & 15;
  const int srow = l >> 3;
  const int gcol = ((l & 7) ^ srow) * 8;

  const short* kTb = kT + (size_t)b * 1024 * 256;
  const short* vTb = vT + (size_t)b * 256 * 1024;
  const float* sB = s_buf + b * 1024;

  // stage resident A (kT m-stripe 64x256) into 4 swizzled panels
  {
    const short* Am = kTb + (size_t)bm * 64 * 256;
    #pragma unroll
    for (int ks = 0; ks < 4; ++ks)
      #pragma unroll
      for (int j2 = 0; j2 < 2; ++j2) {
        int s2 = w * 2 + j2;
        gll16(Am + (size_t)(s2 * 8 + srow) * 256 + ks * 64 + gcol,
              Apan + ks * 8192 + s2 * 1024);
      }
  }
  // prefetch stage 0 (chunk 0, S ks=0) into Bst[0]
  #pragma unroll
  for (int j = 0; j < 4; ++j) {
    int s = w * 4 + j;
    gll16(kTb + (size_t)(s * 8 + srow) * 256 + gcol, Bst + s * 1024);
  }

  float sm[4][4];
  #pragma unroll
  for (int mt = 0; mt < 4; ++mt)
    #pragma unroll
    for (int r = 0; r < 4; ++r) sm[mt][r] = sB[bm * 64 + mt * 16 + q * 4 + r];

  f32x4 zz = {0.f, 0.f, 0.f, 0.f};
  f32x4 acc_o[4][4];
  #pragma unroll
  for (int mt = 0; mt < 4; ++mt)
    #pragma unroll
    for (int ct = 0; ct < 4; ++ct) acc_o[mt][ct] = zz;
  f32x4 acc_s[4][2];
  float rowsum[4][4];
  #pragma unroll
  for (int mt = 0; mt < 4; ++mt)
    #pragma unroll
    for (int r = 0; r < 4; ++r) rowsum[mt][r] = 0.f;

  const float sc1 = 1.0f / 16384.0f;             // (1/M)/16
  const float sc2 = 1.0f / 16777216.0f;          // (1/M^2)/16

  for (int g = 0; g < 64; ++g) {
    const int gs = g & 7;
    const int n0 = (g >> 3) * 128;
    __syncthreads();                             // drains prefetch of stage g
    // ---- issue prefetch for stage g+1 into the other buffer ----
    if (g < 63) {
      const int g1 = g + 1, gs1 = g1 & 7, n1 = (g1 >> 3) * 128;
      char* nb = Bst + (g1 & 1) * 16384;
      if (gs1 < 4) {
        #pragma unroll
        for (int j = 0; j < 4; ++j) {
          int s = w * 4 + j;
          gll16(kTb + (size_t)(n1 + s * 8 + srow) * 256 + gs1 * 64 + gcol,
                nb + s * 1024);
        }
      } else {
        int kh = (gs1 - 4) >> 1, ch = (gs1 - 4) & 1;
        #pragma unroll
        for (int j = 0; j < 4; ++j) {
          int s = w * 4 + j;
          gll16(vTb + (size_t)(ch * 128 + s * 8 + srow) * 1024 + n1 + kh * 64 + gcol,
                nb + s * 1024);
        }
      }
    }
    // ---- compute stage g from its buffer (filled last stage) ----
    char* cb = Bst + (g & 1) * 16384;
    if (gs < 4) {
      if (gs == 0) {
        #pragma unroll
        for (int mt = 0; mt < 4; ++mt)
          #pragma unroll
          for (int nt = 0; nt < 2; ++nt) acc_s[mt][nt] = zz;
      }
      #pragma unroll
      for (int kq = 0; kq < 2; ++kq) {
        int sw = ((kq * 4 + q) ^ (i & 7)) * 16;
        bf8 af[4], bq2[2];
        #pragma unroll
        for (int mt = 0; mt < 4; ++mt)
          af[mt] = *(const bf8*)(Apan + gs * 8192 + (mt * 16 + i) * 128 + sw);
        #pragma unroll
        for (int nt = 0; nt < 2; ++nt)
          bq2[nt] = *(const bf8*)(cb + (w * 32 + nt * 16 + i) * 128 + sw);
        #pragma unroll
        for (int mt = 0; mt < 4; ++mt)
          #pragma unroll
          for (int nt = 0; nt < 2; ++nt)
            acc_s[mt][nt] = MFMA16(af[mt], bq2[nt], acc_s[mt][nt]);
      }
      if (gs == 3) {
        // exp -> P panels (A-operand layout), rowsum accumulate.
        // Next stage's sync orders these writes before PV reads.
        float sn0 = sB[n0 + w * 32 + i];
        float sn1 = sB[n0 + w * 32 + 16 + i];
        #pragma unroll
        for (int nt = 0; nt < 2; ++nt) {
          float sn = nt ? sn1 : sn0;
          int nl = w * 32 + nt * 16 + i;
          char* pbase = Ppan + (nl >> 6) * 8192 + (nl & 7) * 2;
          int gchunk = (nl >> 3) & 7;
          #pragma unroll
          for (int mt = 0; mt < 4; ++mt)
            #pragma unroll
            for (int r = 0; r < 4; ++r) {
              int ml = mt * 16 + q * 4 + r;
              float p = __expf(acc_s[mt][nt][r] * sc1 - sm[mt][r] * sn * sc2);
              rowsum[mt][r] += p;
              *(short*)(pbase + ml * 128 + ((gchunk ^ (ml & 7)) * 16)) = f2bf(p);
            }
        }
      }
    } else {
      const int kh = (gs - 4) >> 1, ch = (gs - 4) & 1;
      #pragma unroll
      for (int kq = 0; kq < 2; ++kq) {
        int sw = ((kq * 4 + q) ^ (i & 7)) * 16;
        bf8 ap[4], bv2[2];
        #pragma unroll
        for (int mt = 0; mt < 4; ++mt)
          ap[mt] = *(const bf8*)(Ppan + kh * 8192 + (mt * 16 + i) * 128 + sw);
        #pragma unroll
        for (int ct = 0; ct < 2; ++ct)
          bv2[ct] = *(const bf8*)(cb + (w * 32 + ct * 16 + i) * 128 + sw);
        #pragma unroll
        for (int mt = 0; mt < 4; ++mt)
          #pragma unroll
          for (int ct = 0; ct < 2; ++ct)
            acc_o[mt][ch * 2 + ct] = MFMA16(ap[mt], bv2[ct], acc_o[mt][ch * 2 + ct]);
      }
    }
  }
  // ---- softmax rowsums: wave-reduce over i, block-reduce over waves ----
  #pragma unroll
  for (int mask = 1; mask <= 8; mask <<= 1)
    #pragma unroll
    for (int mt = 0; mt < 4; ++mt)
      #pragma unroll
      for (int r = 0; r < 4; ++r) rowsum[mt][r] += __shfl_xor(rowsum[mt][r], mask, 64);
  __syncthreads();                               // all PV P-reads done; reuse Ppan
  float* rs = (float*)Ppan;                      // [4 waves][64 m]
  if (i == 0) {
    #pragma unroll
    for (int mt = 0; mt < 4; ++mt)
      #pragma unroll
      for (int r = 0; r < 4; ++r)
        rs[w * 64 + mt * 16 + q * 4 + r] = rowsum[mt][r];
  }
  __syncthreads();
  float rinv[4][4];
  #pragma unroll
  for (int mt = 0; mt < 4; ++mt)
    #pragma unroll
    for (int r = 0; r < 4; ++r) {
      int m = mt * 16 + q * 4 + r;
      rinv[mt][r] = 1.0f / (rs[m] + rs[64 + m] + rs[128 + m] + rs[192 + m]);
    }
  // ---- normalize + OB write via block-cooperative LDS restage (32KB) ----
  // acc_o[mt][ctg] holds c = (ctg>>1)*128 + w*32 + (ctg&1)*16 + i.
  // OB layout: row = (m&3)*256 + c, col = m>>2; this block owns cols bm*16..+16.
  short* ob = (short*)Bst;                       // 1024 rows x 16 shorts
  #pragma unroll
  for (int mt = 0; mt < 4; ++mt)
    #pragma unroll
    for (int ctg = 0; ctg < 4; ++ctg) {
      int cg = (ctg >> 1) * 128 + w * 32 + (ctg & 1) * 16 + i;
      #pragma unroll
      for (int r = 0; r < 4; ++r)
        ob[(r * 256 + cg) * 16 + mt * 4 + q] = f2bf(acc_o[mt][ctg][r] * rinv[mt][r]);
    }
  __syncthreads();
  short* obg = OB + (size_t)b * 1024 * 256;
  #pragma unroll
  for (int jj = 0; jj < 8; ++jj) {
    int lin = jj * 256 + tid;
    int row = lin >> 1, chh = lin & 1;
    *(bf8*)(obg + (size_t)row * 256 + bm * 16 + chh * 8) =
        *(const bf8*)(ob + row * 16 + chh * 8);
  }
}

// ---------------- K3: output projection + bias + residual ----------------
__global__ __launch_bounds__(256, 2) void k3_out(const short* __restrict__ Wo_bf,
                                                 const short* __restrict__ OB,
                                                 const float* __restrict__ bo,
                                                 const float* __restrict__ x,
                                                 float* __restrict__ out) {
  __shared__ __attribute__((aligned(16))) char smem[32768];
  f32x4 acc[4][4];
  int bm = blockIdx.x, bn = blockIdx.y, b = blockIdx.z;
  gemm_core(Wo_bf + (size_t)bm * 128 * 256,
            OB + ((size_t)b * 1024 + bn * 128) * 256, 256, 256, 4, smem, acc);
  int tid = threadIdx.x;
  int w = tid >> 6, l = tid & 63, q = l >> 4, i = l & 15;
  int wm = w & 1, wn = w >> 1;
  int oloc = bm * 128 + wm * 64, sploc = bn * 128 + wn * 64;
  #pragma unroll
  for (int mt = 0; mt < 4; ++mt)
    #pragma unroll
    for (int r = 0; r < 4; ++r) {
      int o = oloc + mt * 16 + q * 4 + r;
      float bias = bo[o];
      #pragma unroll
      for (int nt = 0; nt < 4; ++nt) {
        int sp = sploc + nt * 16 + i;
        size_t idx = ((size_t)b * 512 + o) * 1024 + sp;
        out[idx] = acc[mt][nt][r] + bias + x[idx];
      }
    }
}

extern "C" void kernel_launch(void* const* d_in, const int* in_sizes, int n_in,
                              void* d_out, int out_size, void* d_ws, size_t ws_size,
                              hipStream_t stream) {
  (void)in_sizes; (void)n_in; (void)out_size; (void)ws_size;
  const float* x  = (const float*)d_in[0];
  const float* Wk = (const float*)d_in[1];
  const float* bk = (const float*)d_in[2];
  const float* Wv = (const float*)d_in[3];
  const float* bv = (const float*)d_in[4];
  const float* Wo = (const float*)d_in[5];
  const float* bo = (const float*)d_in[6];
  float* out = (float*)d_out;
  char* ws = (char*)d_ws;

  // ws layout (~68.5 MB), time-aliased:
  //   [0,32M)   : xT (P0->K1, 32 MB) then OB (K2->K3, 16 MB)
  //   [32M,48M) : kT (K1->K2)
  //   [48M,64M) : vT (K1->K2)
  //   [64M,...) : weights + reduction buffers
  short* xT     = (short*)(ws);
  short* OB     = (short*)(ws);
  short* kTb    = (short*)(ws + 33554432);
  short* vTb    = (short*)(ws + 50331648);
  short* Wkv_bf = (short*)(ws + 67108864);
  short* Wo_bf  = (short*)(ws + 67633152);
  float* s_part = (float*)(ws + 67895296);
  float* s_buf  = (float*)(ws + 68419584);

  p0_xpose<<<dim3(8, 16, 32), 256, 0, stream>>>(x, xT);
  w0_weights<<<1536, 256, 0, stream>>>(Wk, Wv, Wo, Wkv_bf, Wo_bf);
  k1_kv<<<dim3(256, 4), 256, 0, stream>>>(xT, Wkv_bf, bk, bv, kTb, vTb, s_part);
  k1b_sum<<<128, 256, 0, stream>>>(s_part, s_buf);
  k2_fused<<<dim3(16, 32), 256, 0, stream>>>(kTb, vTb, s_buf, OB);
  k3_out<<<dim3(4, 8, 32), 256, 0, stream>>>(Wo_bf, OB, bo, x, out);
}